// Round 11
// baseline (409.258 us; speedup 1.0000x reference)
//
#include <hip/hip_runtime.h>
#include <hip/hip_bf16.h>
#include <math.h>

typedef __hip_bfloat16 bf16;
typedef __bf16 v8bf __attribute__((ext_vector_type(8)));
typedef float v4f __attribute__((ext_vector_type(4)));

#define BN_SCALE 0.9999950000374997f
#define NPTS 1024
#define NB 4
#define TW 40  // LDS tile row stride in bf16 (80B: 2-way bank alias only = free)

__device__ __forceinline__ float b2f(bf16 v) { return __bfloat162float(v); }
__device__ __forceinline__ bf16 f2b(float v) { return __float2bfloat16(v); }
// dtype-flag-aware load: isf=1 -> fp32 data, isf=0 -> bf16 data
__device__ __forceinline__ float ldw(const void* p, size_t i, int isf) {
    return isf ? ((const float*)p)[i] : b2f(((const bf16*)p)[i]);
}
// order-preserving float<->uint transform (monotone increasing)
__device__ __forceinline__ unsigned ordf(float f) {
    unsigned u = __float_as_uint(f);
    return (u & 0x80000000u) ? ~u : (u | 0x80000000u);
}
__device__ __forceinline__ float iordf(unsigned u) {
    return (u & 0x80000000u) ? __uint_as_float(u ^ 0x80000000u) : __uint_as_float(~u);
}

// ---------------- dtype probe (fp32=1 / bf16=0) + pooled init ----------------
__global__ void k_probe(const void* xraw, int* flag, unsigned* pooledU) {
    __shared__ int cnt[256];
    const unsigned short* u = (const unsigned short*)xraw;
    int t = threadIdx.x, c = 0;
    for (int i = t; i < 8192; i += 256) {
        unsigned short v = u[i];
        int e = (v >> 7) & 0xFF;
        int m = v & 0x7F;
        if (e == 0xFF || e >= 141 || (e == 0 && m != 0)) c++;
    }
    cnt[t] = c;
    for (int i = t; i < 2048; i += 256) pooledU[i] = 0u;  // 0 < ordf(any finite)
    __syncthreads();
    for (int off = 128; off > 0; off >>= 1) {
        if (t < off) cnt[t] += cnt[t + off];
        __syncthreads();
    }
    if (t == 0) *flag = (cnt[0] > 200) ? 1 : 0;
}

// ---------------- fused prep: all weight splits + x padding + sq, one launch ----------------
// Whi/Wlo element segments: L1 st[128][32] @0, L2 st[256][64] @4096, L3 st[512][128] @20480,
// L4 st[1024][256] @86016, W5 [512][960] @348160; then xpad points @839680..843776
__global__ void k_prep(const void* __restrict__ W1, const void* __restrict__ W2,
                       const void* __restrict__ W3, const void* __restrict__ W4,
                       const void* __restrict__ W5, const void* __restrict__ x,
                       bf16* __restrict__ Whi, bf16* __restrict__ Wlo,
                       bf16* __restrict__ xph, bf16* __restrict__ xpl, float* __restrict__ sq,
                       const int* __restrict__ flag) {
    int isf = *flag;
    int idx = blockIdx.x * 256 + threadIdx.x;
    if (idx < 839680) {
        const void* src; int C, O, Kpad, two, local;
        if (idx < 4096)        { src = W1; C = 3;   O = 64;  Kpad = 32;  two = 1; local = idx; }
        else if (idx < 20480)  { src = W2; C = 64;  O = 128; Kpad = 64;  two = 1; local = idx - 4096; }
        else if (idx < 86016)  { src = W3; C = 128; O = 256; Kpad = 128; two = 1; local = idx - 20480; }
        else if (idx < 348160) { src = W4; C = 256; O = 512; Kpad = 256; two = 1; local = idx - 86016; }
        else                   { src = W5; C = 960; O = 512; Kpad = 960; two = 0; local = idx - 348160; }
        int r = local / Kpad, c = local % Kpad;
        float wv = 0.f;
        if (c < C) {
            size_t off;
            if (two) off = (r < O) ? (size_t)r * 2 * C + c : (size_t)(r - O) * 2 * C + C + c;
            else     off = (size_t)r * C + c;
            wv = ldw(src, off, isf);
        }
        bf16 h = f2b(wv);
        Whi[idx] = h;
        Wlo[idx] = f2b(wv - b2f(h));
    } else if (idx < 843776) {
        int p = idx - 839680;       // point index: z*1024 + n
        int z = p >> 10, n = p & 1023;
        bf16* ph = xph + (size_t)z * NPTS * 32;
        bf16* pl = xpl + (size_t)z * NPTS * 32;
        float s = 0.f;
        for (int c = 0; c < 32; c++) {
            float v = (c < 3) ? ldw(x, (size_t)z * NPTS * 3 + n * 3 + c, isf) : 0.f;
            bf16 h = f2b(v);
            ph[n * 32 + c] = h;
            pl[n * 32 + c] = f2b(v - b2f(h));
            s += v * v;
        }
        sq[z * NPTS + n] = s;
    }
}

// fill a 64x32 bf16 tile (rows stride ld) into LDS [64][TW]; 256 threads x 16B
__device__ __forceinline__ void fillA(bf16* dst, const bf16* srcRowBase, int ld) {
    int t = threadIdx.x; int r = t >> 2; int kq = (t & 3) << 3;
    *(float4*)(dst + r * TW + kq) = *(const float4*)(srcRowBase + (size_t)r * ld + kq);
}
// MFMA fragment: sub-tile 'sub' (16 rows), lane l: row=sub*16+(l&15), k=(l>>4)*8
__device__ __forceinline__ v8bf ldfrag(const bf16* tile, int sub, int l) {
    return *(const v8bf*)(tile + (size_t)(sub * 16 + (l & 15)) * TW + ((l >> 4) << 3));
}

// ---------------- fused layer stage A: dist (upper-tri tiles) + st, one launch ----------------
// grid.x = 136 + 16*nTilesO, grid.y = NB
__global__ __launch_bounds__(256) void k_layer_a(const bf16* __restrict__ Xhi, const bf16* __restrict__ Xlo,
                                                 int ld, int Kpad, size_t xstride,
                                                 const bf16* __restrict__ Whi, const bf16* __restrict__ Wlo,
                                                 int O, const float* __restrict__ sqg,
                                                 float* __restrict__ Dg, float* __restrict__ Pg,
                                                 const int* __restrict__ flag) {
    int z = blockIdx.y;
    const bf16* Xh = Xhi + (size_t)z * xstride;
    const bf16* Xl = Xlo + (size_t)z * xstride;
    __shared__ alignas(16) bf16 Ah[64 * TW], Al[64 * TW], Bh[64 * TW], Bl[64 * TW];
    int w = threadIdx.x >> 6, l = threadIdx.x & 63;
    int quad = l >> 4, col = l & 15;
    v4f zero = {0.f, 0.f, 0.f, 0.f};
    v4f acc[4] = {zero, zero, zero, zero};
    int bi = blockIdx.x;

    if (bi < 136) {
        // ---- dist tile: triangular decode, bx >= by ----
        int bx = 0;
        while ((((bx + 1) * (bx + 2)) >> 1) <= bi) bx++;
        int by = bi - ((bx * (bx + 1)) >> 1);
        const float* sq = sqg + z * NPTS;
        float* D = Dg + (size_t)z * NPTS * NPTS;
        int n0 = by * 64, m0 = bx * 64;
        for (int k0 = 0; k0 < Kpad; k0 += 32) {
            __syncthreads();
            fillA(Ah, Xh + (size_t)n0 * ld + k0, ld);
            fillA(Bh, Xh + (size_t)m0 * ld + k0, ld);
            fillA(Al, Xl + (size_t)n0 * ld + k0, ld);
            fillA(Bl, Xl + (size_t)m0 * ld + k0, ld);
            __syncthreads();
            v8bf ah = ldfrag(Ah, w, l);
            v8bf al = ldfrag(Al, w, l);
#pragma unroll
            for (int nt = 0; nt < 4; nt++) {
                v8bf bh = ldfrag(Bh, nt, l);
                v8bf bl = ldfrag(Bl, nt, l);
                acc[nt] = __builtin_amdgcn_mfma_f32_16x16x32_bf16(ah, bh, acc[nt], 0, 0, 0);
                acc[nt] = __builtin_amdgcn_mfma_f32_16x16x32_bf16(ah, bl, acc[nt], 0, 0, 0);
                acc[nt] = __builtin_amdgcn_mfma_f32_16x16x32_bf16(al, bh, acc[nt], 0, 0, 0);
            }
        }
        int nb = n0 + 16 * w + quad * 4;
        float sm[4];
#pragma unroll
        for (int nt = 0; nt < 4; nt++) sm[nt] = sq[m0 + nt * 16 + col];
#pragma unroll
        for (int r = 0; r < 4; r++) {
            float sn = sq[nb + r];
#pragma unroll
            for (int nt = 0; nt < 4; nt++) {
                float d = 2.f * acc[nt][r] - sn - sm[nt];
                int m = m0 + nt * 16 + col;
                D[(size_t)(nb + r) * NPTS + m] = d;
                if (bx != by) D[(size_t)m * NPTS + nb + r] = d;
            }
        }
    } else {
        // ---- st tile ----
        int isf = *flag;
        int nTilesO = (2 * O) >> 6;
        int s = bi - 136;
        int n0 = (s % nTilesO) * 64;   // weight-row tile (over 2O)
        int m0 = (s / nTilesO) * 64;   // point tile (over 1024)
        int N2 = 2 * O;
        float* P = Pg + (size_t)z * NPTS * N2;
        for (int k0 = 0; k0 < Kpad; k0 += 32) {
            __syncthreads();
            fillA(Ah, Xh + (size_t)m0 * ld + k0, ld);
            fillA(Al, Xl + (size_t)m0 * ld + k0, ld);
            fillA(Bh, Whi + (size_t)n0 * Kpad + k0, Kpad);
            if (isf) fillA(Bl, Wlo + (size_t)n0 * Kpad + k0, Kpad);
            __syncthreads();
            v8bf ah = ldfrag(Ah, w, l);
            v8bf al = ldfrag(Al, w, l);
#pragma unroll
            for (int nt = 0; nt < 4; nt++) {
                v8bf bh = ldfrag(Bh, nt, l);
                acc[nt] = __builtin_amdgcn_mfma_f32_16x16x32_bf16(ah, bh, acc[nt], 0, 0, 0);
                acc[nt] = __builtin_amdgcn_mfma_f32_16x16x32_bf16(al, bh, acc[nt], 0, 0, 0);
                if (isf) {
                    v8bf bl = ldfrag(Bl, nt, l);
                    acc[nt] = __builtin_amdgcn_mfma_f32_16x16x32_bf16(ah, bl, acc[nt], 0, 0, 0);
                }
            }
        }
        int rb = m0 + 16 * w + quad * 4;
#pragma unroll
        for (int r = 0; r < 4; r++)
#pragma unroll
            for (int nt = 0; nt < 4; nt++)
                P[(size_t)(rb + r) * N2 + n0 + nt * 16 + col] = acc[nt][r];
    }
}

// ---------------- fused layer stage B: top-20 (wave 0, register-resident) + gather-max ----------------
__global__ void k_layer_b(const float* __restrict__ Dg, const float* __restrict__ Pg,
                          const void* __restrict__ g, const void* __restrict__ bias, int O,
                          bf16* __restrict__ xhOut, bf16* __restrict__ xlOut,
                          float* __restrict__ sqOut, int writeSq, const int* __restrict__ flag) {
    __shared__ int id[20];
    __shared__ float red[8];
    int isf = *flag;
    int z = blockIdx.y;
    int n = blockIdx.x;
    int o = threadIdx.x;  // blockDim.x == O
    int l = o & 63;
    if (o < 64) {  // wave 0: top-20 of D row n (jax tie-break: value desc, index asc)
        const float* Dr = Dg + (size_t)z * NPTS * NPTS + (size_t)n * NPTS;
        float v[16];
#pragma unroll
        for (int j = 0; j < 16; j++) v[j] = Dr[j * 64 + l];
        for (int s = 0; s < 20; s++) {
            float bv = v[0]; int bj = 0;
#pragma unroll
            for (int j = 1; j < 16; j++)
                if (v[j] > bv) { bv = v[j]; bj = j; }   // ascending keeps min j on tie
            int bidx = bj * 64 + l;
#pragma unroll
            for (int off = 1; off < 64; off <<= 1) {    // xor butterfly: all lanes converge
                float ov = __shfl_xor(bv, off);
                int   oi = __shfl_xor(bidx, off);
                if (ov > bv || (ov == bv && oi < bidx)) { bv = ov; bidx = oi; }
            }
            if (l == 0) id[s] = bidx;
            if ((bidx & 63) == l) {                     // owning lane evicts
                int ej = bidx >> 6;
#pragma unroll
                for (int j = 0; j < 16; j++)
                    if (j == ej) v[j] = -__builtin_inff();
            }
        }
    }
    __syncthreads();
    int N2 = 2 * O;
    const float* P = Pg + (size_t)z * NPTS * N2;
    float tv = P[(size_t)n * N2 + O + o] - P[(size_t)n * N2 + o];
    float scl = ldw(g, o, isf) * BN_SCALE;
    float bv2 = ldw(bias, o, isf);
    float acc = -__builtin_inff();
    for (int j = 0; j < 20; j++) {
        int m = id[j];
        float v = P[(size_t)m * N2 + o] + tv;
        float z2 = v * scl + bv2;
        z2 = z2 > 0.f ? z2 : 0.2f * z2;
        acc = fmaxf(acc, z2);
    }
    bf16 hi = f2b(acc);
    bf16 lo = f2b(acc - b2f(hi));
    xhOut[(size_t)z * NPTS * 960 + (size_t)n * 960 + o] = hi;
    xlOut[(size_t)z * NPTS * 960 + (size_t)n * 960 + o] = lo;
    if (writeSq) {
        float xv = b2f(hi) + b2f(lo);
        float s = xv * xv;
#pragma unroll
        for (int off = 32; off > 0; off >>= 1) s += __shfl_down(s, off);
        if ((o & 63) == 0) red[o >> 6] = s;
        __syncthreads();
        if (o == 0) {
            float tot = 0.f;
            for (int i = 0; i < (O >> 6); i++) tot += red[i];
            sqOut[z * NPTS + n] = tot;
        }
    }
}

// ---------------- conv5 via MFMA (pre-split W5) + fused affine/lrelu/max-pool ----------------
__global__ __launch_bounds__(256) void k_conv5(const bf16* __restrict__ Xhi, const bf16* __restrict__ Xlo,
                                               const bf16* __restrict__ Whi, const bf16* __restrict__ Wlo,
                                               const void* __restrict__ g, const void* __restrict__ bias,
                                               unsigned* __restrict__ pooledU,
                                               const int* __restrict__ flag) {
    int isf = *flag;
    int z = blockIdx.z;
    const bf16* Xh = Xhi + (size_t)z * NPTS * 960;
    const bf16* Xl = Xlo + (size_t)z * NPTS * 960;
    __shared__ alignas(16) bf16 Ah[64 * TW], Al[64 * TW], Bh[64 * TW], Bl[64 * TW];
    __shared__ float red[4][4][16];
    int m0 = blockIdx.y * 64, o0 = blockIdx.x * 64;
    int w = threadIdx.x >> 6, l = threadIdx.x & 63;
    v4f zero = {0.f, 0.f, 0.f, 0.f};
    v4f acc[4] = {zero, zero, zero, zero};
    for (int k0 = 0; k0 < 960; k0 += 32) {
        __syncthreads();
        fillA(Ah, Xh + (size_t)m0 * 960 + k0, 960);
        fillA(Al, Xl + (size_t)m0 * 960 + k0, 960);
        fillA(Bh, Whi + (size_t)o0 * 960 + k0, 960);
        if (isf) fillA(Bl, Wlo + (size_t)o0 * 960 + k0, 960);
        __syncthreads();
        v8bf ah = ldfrag(Ah, w, l);
        v8bf al = ldfrag(Al, w, l);
#pragma unroll
        for (int nt = 0; nt < 4; nt++) {
            v8bf bh = ldfrag(Bh, nt, l);
            acc[nt] = __builtin_amdgcn_mfma_f32_16x16x32_bf16(ah, bh, acc[nt], 0, 0, 0);
            acc[nt] = __builtin_amdgcn_mfma_f32_16x16x32_bf16(al, bh, acc[nt], 0, 0, 0);
            if (isf) {
                v8bf bl = ldfrag(Bl, nt, l);
                acc[nt] = __builtin_amdgcn_mfma_f32_16x16x32_bf16(ah, bl, acc[nt], 0, 0, 0);
            }
        }
    }
    int quad = l >> 4, col = l & 15;
#pragma unroll
    for (int nt = 0; nt < 4; nt++) {
        int o = o0 + nt * 16 + col;
        float scl = ldw(g, o, isf) * BN_SCALE;
        float bi = ldw(bias, o, isf);
        float ym = -__builtin_inff();
#pragma unroll
        for (int r = 0; r < 4; r++) {
            float v = acc[nt][r] * scl + bi;
            v = v > 0.f ? v : 0.2f * v;
            ym = fmaxf(ym, v);
        }
        ym = fmaxf(ym, __shfl_down(ym, 32));
        ym = fmaxf(ym, __shfl_down(ym, 16));
        if (quad == 0) red[w][nt][col] = ym;
    }
    __syncthreads();
    if (threadIdx.x < 64) {
        int nt = threadIdx.x >> 4, c = threadIdx.x & 15;
        float m = fmaxf(fmaxf(red[0][nt][c], red[1][nt][c]), fmaxf(red[2][nt][c], red[3][nt][c]));
        atomicMax(&pooledU[z * 512 + o0 + nt * 16 + c], ordf(m));
    }
}

// ---------------- final linear: coalesced wave-per-output ----------------
__global__ void k_final(const unsigned* __restrict__ pooledU, const void* __restrict__ We,
                        void* __restrict__ out, const int* __restrict__ flag) {
    __shared__ float p[512];
    int isf = *flag;
    int b = blockIdx.x >> 2, fb = blockIdx.x & 3;
    int t = threadIdx.x, w = t >> 6, l = t & 63;
    for (int i = t; i < 512; i += 256) p[i] = iordf(pooledU[b * 512 + i]);
    __syncthreads();
    for (int it = 0; it < 16; it++) {
        int f = fb * 64 + w * 16 + it;
        float s = 0.f;
        size_t base = (size_t)f * 512 + l * 8;
#pragma unroll
        for (int j = 0; j < 8; j++) s += p[l * 8 + j] * ldw(We, base + j, isf);
#pragma unroll
        for (int off = 32; off > 0; off >>= 1) s += __shfl_down(s, off);
        if (l == 0) {
            if (isf) ((float*)out)[b * 256 + f] = s;
            else     ((bf16*)out)[b * 256 + f] = f2b(s);
        }
    }
}

extern "C" void kernel_launch(void* const* d_in, const int* in_sizes, int n_in,
                              void* d_out, int out_size, void* d_ws, size_t ws_size,
                              hipStream_t stream) {
    const void* x  = d_in[0];
    const void* Wl[4] = { d_in[1], d_in[4], d_in[7], d_in[10] };
    const void* gl[4] = { d_in[2], d_in[5], d_in[8], d_in[11] };
    const void* bl[4] = { d_in[3], d_in[6], d_in[9], d_in[12] };
    const void* W5 = d_in[13];
    const void* g5 = d_in[14];
    const void* b5 = d_in[15];
    const void* We = d_in[16];

    // workspace layout (bytes), total ~53.2 MB (ws ~256 MiB per round-9 fill evidence)
    char* base = (char*)d_ws;
    bf16*     xc_hi   = (bf16*)(base);                  // 7,864,320
    bf16*     xc_lo   = (bf16*)(base + 7864320);        // 7,864,320
    bf16*     xpadh   = (bf16*)(base + 15728640);       // 262,144
    bf16*     xpadl   = (bf16*)(base + 15990784);       // 262,144
    float*    Dbuf    = (float*)(base + 16252928);      // 16,777,216
    float*    Pbuf    = (float*)(base + 33030144);      // 16,777,216
    bf16*     Whi     = (bf16*)(base + 49807360);       // 1,679,360
    bf16*     Wlo     = (bf16*)(base + 51486720);       // 1,679,360
    unsigned* pooledU = (unsigned*)(base + 53166080);   // 8,192
    float*    sq      = (float*)(base + 53174272);      // 16,384
    int*      flag    = (int*)(base + 53190656);        // 4

    const int Kpad[4]   = { 32, 64, 128, 256 };
    const int Os[4]     = { 64, 128, 256, 512 };
    const int Woff[5]   = { 0, 4096, 20480, 86016, 348160 };
    const int colIn[4]  = { 0, 0, 64, 192 };
    const int colOut[4] = { 0, 64, 192, 448 };

    k_probe<<<1, 256, 0, stream>>>(x, flag, pooledU);
    k_prep<<<3296, 256, 0, stream>>>(Wl[0], Wl[1], Wl[2], Wl[3], W5, x,
                                     Whi, Wlo, xpadh, xpadl, sq, flag);

    for (int l = 0; l < 4; l++) {
        int O = Os[l];
        int nTilesO = (2 * O) >> 6;
        const bf16* Xh = (l == 0) ? xpadh : (xc_hi + colIn[l]);
        const bf16* Xl = (l == 0) ? xpadl : (xc_lo + colIn[l]);
        int ld = (l == 0) ? 32 : 960;
        size_t xstr = (l == 0) ? (size_t)NPTS * 32 : (size_t)NPTS * 960;
        k_layer_a<<<dim3(136 + 16 * nTilesO, NB), 256, 0, stream>>>(
            Xh, Xl, ld, Kpad[l], xstr, Whi + Woff[l], Wlo + Woff[l], O, sq, Dbuf, Pbuf, flag);
        k_layer_b<<<dim3(NPTS, NB), O, 0, stream>>>(
            Dbuf, Pbuf, gl[l], bl[l], O, xc_hi + colOut[l], xc_lo + colOut[l], sq, l < 3, flag);
    }
    k_conv5<<<dim3(8, 16, NB), 256, 0, stream>>>(xc_hi, xc_lo, Whi + Woff[4], Wlo + Woff[4],
                                                 g5, b5, pooledU, flag);
    k_final<<<16, 256, 0, stream>>>(pooledU, We, d_out, flag);
}

// Round 12
// 353.089 us; speedup vs baseline: 1.1591x; 1.1591x over previous
//
#include <hip/hip_runtime.h>
#include <hip/hip_bf16.h>
#include <math.h>

typedef __hip_bfloat16 bf16;
typedef __bf16 v8bf __attribute__((ext_vector_type(8)));
typedef float v4f __attribute__((ext_vector_type(4)));

#define BN_SCALE 0.9999950000374997f
#define NPTS 1024
#define NB 4
#define TW 40  // LDS tile row stride in bf16 (80B: 2-way bank alias only = free)

__device__ __forceinline__ float b2f(bf16 v) { return __bfloat162float(v); }
__device__ __forceinline__ bf16 f2b(float v) { return __float2bfloat16(v); }
// dtype-flag-aware load: isf=1 -> fp32 data, isf=0 -> bf16 data
__device__ __forceinline__ float ldw(const void* p, size_t i, int isf) {
    return isf ? ((const float*)p)[i] : b2f(((const bf16*)p)[i]);
}
// order-preserving float<->uint transform (monotone increasing)
__device__ __forceinline__ unsigned ordf(float f) {
    unsigned u = __float_as_uint(f);
    return (u & 0x80000000u) ? ~u : (u | 0x80000000u);
}
__device__ __forceinline__ float iordf(unsigned u) {
    return (u & 0x80000000u) ? __uint_as_float(u ^ 0x80000000u) : __uint_as_float(~u);
}

// ---------------- dtype probe (fp32=1 / bf16=0) + pooled init ----------------
__global__ void k_probe(const void* xraw, int* flag, unsigned* pooledU) {
    __shared__ int cnt[256];
    const unsigned short* u = (const unsigned short*)xraw;
    int t = threadIdx.x, c = 0;
    for (int i = t; i < 8192; i += 256) {
        unsigned short v = u[i];
        int e = (v >> 7) & 0xFF;
        int m = v & 0x7F;
        if (e == 0xFF || e >= 141 || (e == 0 && m != 0)) c++;
    }
    cnt[t] = c;
    for (int i = t; i < 2048; i += 256) pooledU[i] = 0u;  // 0 < ordf(any finite)
    __syncthreads();
    for (int off = 128; off > 0; off >>= 1) {
        if (t < off) cnt[t] += cnt[t + off];
        __syncthreads();
    }
    if (t == 0) *flag = (cnt[0] > 200) ? 1 : 0;
}

// ---------------- fused prep: all weight splits + x padding + sq, one launch ----------------
__global__ void k_prep(const void* __restrict__ W1, const void* __restrict__ W2,
                       const void* __restrict__ W3, const void* __restrict__ W4,
                       const void* __restrict__ W5, const void* __restrict__ x,
                       bf16* __restrict__ Whi, bf16* __restrict__ Wlo,
                       bf16* __restrict__ xph, bf16* __restrict__ xpl, float* __restrict__ sq,
                       const int* __restrict__ flag) {
    int isf = *flag;
    int idx = blockIdx.x * 256 + threadIdx.x;
    if (idx < 839680) {
        const void* src; int C, O, Kpad, two, local;
        if (idx < 4096)        { src = W1; C = 3;   O = 64;  Kpad = 32;  two = 1; local = idx; }
        else if (idx < 20480)  { src = W2; C = 64;  O = 128; Kpad = 64;  two = 1; local = idx - 4096; }
        else if (idx < 86016)  { src = W3; C = 128; O = 256; Kpad = 128; two = 1; local = idx - 20480; }
        else if (idx < 348160) { src = W4; C = 256; O = 512; Kpad = 256; two = 1; local = idx - 86016; }
        else                   { src = W5; C = 960; O = 512; Kpad = 960; two = 0; local = idx - 348160; }
        int r = local / Kpad, c = local % Kpad;
        float wv = 0.f;
        if (c < C) {
            size_t off;
            if (two) off = (r < O) ? (size_t)r * 2 * C + c : (size_t)(r - O) * 2 * C + C + c;
            else     off = (size_t)r * C + c;
            wv = ldw(src, off, isf);
        }
        bf16 h = f2b(wv);
        Whi[idx] = h;
        Wlo[idx] = f2b(wv - b2f(h));
    } else if (idx < 843776) {
        int p = idx - 839680;       // point index: z*1024 + n
        int z = p >> 10, n = p & 1023;
        bf16* ph = xph + (size_t)z * NPTS * 32;
        bf16* pl = xpl + (size_t)z * NPTS * 32;
        float s = 0.f;
        for (int c = 0; c < 32; c++) {
            float v = (c < 3) ? ldw(x, (size_t)z * NPTS * 3 + n * 3 + c, isf) : 0.f;
            bf16 h = f2b(v);
            ph[n * 32 + c] = h;
            pl[n * 32 + c] = f2b(v - b2f(h));
            s += v * v;
        }
        sq[z * NPTS + n] = s;
    }
}

// fill a 64x32 bf16 tile (rows stride ld) into LDS [64][TW]; 256 threads x 16B
__device__ __forceinline__ void fillA(bf16* dst, const bf16* srcRowBase, int ld) {
    int t = threadIdx.x; int r = t >> 2; int kq = (t & 3) << 3;
    *(float4*)(dst + r * TW + kq) = *(const float4*)(srcRowBase + (size_t)r * ld + kq);
}
// MFMA fragment: sub-tile 'sub' (16 rows), lane l: row=sub*16+(l&15), k=(l>>4)*8
__device__ __forceinline__ v8bf ldfrag(const bf16* tile, int sub, int l) {
    return *(const v8bf*)(tile + (size_t)(sub * 16 + (l & 15)) * TW + ((l >> 4) << 3));
}

// ---------------- fused layer stage A: dist (upper-tri tiles) + st ----------------
// 1D grid, XCD-pinned: z = (i>>1)&3, bi = ((i>>3)<<1)|(i&1)  (batch z -> XCDs {2z,2z+1})
__global__ __launch_bounds__(256) void k_layer_a(const bf16* __restrict__ Xhi, const bf16* __restrict__ Xlo,
                                                 int ld, int Kpad, size_t xstride,
                                                 const bf16* __restrict__ Whi, const bf16* __restrict__ Wlo,
                                                 int O, const float* __restrict__ sqg,
                                                 float* __restrict__ Dg, float* __restrict__ Pg,
                                                 const int* __restrict__ flag) {
    int i = blockIdx.x;
    int z = (i >> 1) & 3;
    int bi = ((i >> 3) << 1) | (i & 1);
    const bf16* Xh = Xhi + (size_t)z * xstride;
    const bf16* Xl = Xlo + (size_t)z * xstride;
    __shared__ alignas(16) bf16 Ah[64 * TW], Al[64 * TW], Bh[64 * TW], Bl[64 * TW];
    int w = threadIdx.x >> 6, l = threadIdx.x & 63;
    int quad = l >> 4, col = l & 15;
    v4f zero = {0.f, 0.f, 0.f, 0.f};
    v4f acc[4] = {zero, zero, zero, zero};

    if (bi < 136) {
        // ---- dist tile: triangular decode, bx >= by ----
        int bx = 0;
        while ((((bx + 1) * (bx + 2)) >> 1) <= bi) bx++;
        int by = bi - ((bx * (bx + 1)) >> 1);
        const float* sq = sqg + z * NPTS;
        float* D = Dg + (size_t)z * NPTS * NPTS;
        int n0 = by * 64, m0 = bx * 64;
        for (int k0 = 0; k0 < Kpad; k0 += 32) {
            __syncthreads();
            fillA(Ah, Xh + (size_t)n0 * ld + k0, ld);
            fillA(Bh, Xh + (size_t)m0 * ld + k0, ld);
            fillA(Al, Xl + (size_t)n0 * ld + k0, ld);
            fillA(Bl, Xl + (size_t)m0 * ld + k0, ld);
            __syncthreads();
            v8bf ah = ldfrag(Ah, w, l);
            v8bf al = ldfrag(Al, w, l);
#pragma unroll
            for (int nt = 0; nt < 4; nt++) {
                v8bf bh = ldfrag(Bh, nt, l);
                v8bf bl = ldfrag(Bl, nt, l);
                acc[nt] = __builtin_amdgcn_mfma_f32_16x16x32_bf16(ah, bh, acc[nt], 0, 0, 0);
                acc[nt] = __builtin_amdgcn_mfma_f32_16x16x32_bf16(ah, bl, acc[nt], 0, 0, 0);
                acc[nt] = __builtin_amdgcn_mfma_f32_16x16x32_bf16(al, bh, acc[nt], 0, 0, 0);
            }
        }
        int nb = n0 + 16 * w + quad * 4;
        float sm[4];
#pragma unroll
        for (int nt = 0; nt < 4; nt++) sm[nt] = sq[m0 + nt * 16 + col];
#pragma unroll
        for (int r = 0; r < 4; r++) {
            float sn = sq[nb + r];
#pragma unroll
            for (int nt = 0; nt < 4; nt++) {
                float d = 2.f * acc[nt][r] - sn - sm[nt];
                int m = m0 + nt * 16 + col;
                D[(size_t)(nb + r) * NPTS + m] = d;
                if (bx != by) D[(size_t)m * NPTS + nb + r] = d;
            }
        }
    } else {
        // ---- st tile ----
        int isf = *flag;
        int nTilesO = (2 * O) >> 6;
        int s = bi - 136;
        int n0 = (s % nTilesO) * 64;   // weight-row tile (over 2O)
        int m0 = (s / nTilesO) * 64;   // point tile (over 1024)
        int N2 = 2 * O;
        float* P = Pg + (size_t)z * NPTS * N2;
        for (int k0 = 0; k0 < Kpad; k0 += 32) {
            __syncthreads();
            fillA(Ah, Xh + (size_t)m0 * ld + k0, ld);
            fillA(Al, Xl + (size_t)m0 * ld + k0, ld);
            fillA(Bh, Whi + (size_t)n0 * Kpad + k0, Kpad);
            if (isf) fillA(Bl, Wlo + (size_t)n0 * Kpad + k0, Kpad);
            __syncthreads();
            v8bf ah = ldfrag(Ah, w, l);
            v8bf al = ldfrag(Al, w, l);
#pragma unroll
            for (int nt = 0; nt < 4; nt++) {
                v8bf bh = ldfrag(Bh, nt, l);
                acc[nt] = __builtin_amdgcn_mfma_f32_16x16x32_bf16(ah, bh, acc[nt], 0, 0, 0);
                acc[nt] = __builtin_amdgcn_mfma_f32_16x16x32_bf16(al, bh, acc[nt], 0, 0, 0);
                if (isf) {
                    v8bf bl = ldfrag(Bl, nt, l);
                    acc[nt] = __builtin_amdgcn_mfma_f32_16x16x32_bf16(ah, bl, acc[nt], 0, 0, 0);
                }
            }
        }
        int rb = m0 + 16 * w + quad * 4;
#pragma unroll
        for (int r = 0; r < 4; r++)
#pragma unroll
            for (int nt = 0; nt < 4; nt++)
                P[(size_t)(rb + r) * N2 + n0 + nt * 16 + col] = acc[nt][r];
    }
}

// ---------------- top-k (k=20): register-resident, wave per row, batched ----------------
__global__ __launch_bounds__(256) void k_topk(const float* __restrict__ Dg, int* __restrict__ idx) {
    int z = blockIdx.y;
    int w = threadIdx.x >> 6, l = threadIdx.x & 63;
    int row = blockIdx.x * 4 + w;
    const float* Dr = Dg + (size_t)z * NPTS * NPTS + (size_t)row * NPTS;
    float v[16];
#pragma unroll
    for (int j = 0; j < 16; j++) v[j] = Dr[j * 64 + l];
    for (int s = 0; s < 20; s++) {
        float bv = v[0]; int bj = 0;
#pragma unroll
        for (int j = 1; j < 16; j++)
            if (v[j] > bv) { bv = v[j]; bj = j; }   // ascending keeps min j on tie
        int bi = bj * 64 + l;
#pragma unroll
        for (int off = 1; off < 64; off <<= 1) {   // xor butterfly: all lanes converge
            float ov = __shfl_xor(bv, off);
            int   oi = __shfl_xor(bi, off);
            if (ov > bv || (ov == bv && oi < bi)) { bv = ov; bi = oi; }
        }
        if (l == 0) idx[(z * NPTS + row) * 20 + s] = bi;
        if ((bi & 63) == l) {
            int ej = bi >> 6;
#pragma unroll
            for (int j = 0; j < 16; j++)
                if (j == ej) v[j] = -__builtin_inff();
        }
    }
}

// ---------------- gather + affine + lrelu + max over k -> xc hi/lo; fused sq ----------------
// 1D grid 4096, XCD-pinned: z = (i>>1)&3, n = ((i>>3)<<1)|(i&1) -> P_z stays in XCD-pair L2
__global__ void k_gmax(const float* __restrict__ Pg, const int* __restrict__ idx,
                       const void* __restrict__ g, const void* __restrict__ bias, int O,
                       bf16* __restrict__ xhOut, bf16* __restrict__ xlOut,
                       float* __restrict__ sqOut, int writeSq, const int* __restrict__ flag) {
    __shared__ int id[20];
    __shared__ float red[8];
    int isf = *flag;
    int i = blockIdx.x;
    int z = (i >> 1) & 3;
    int n = ((i >> 3) << 1) | (i & 1);
    int o = threadIdx.x;  // blockDim.x == O
    if (o < 20) id[o] = idx[(z * NPTS + n) * 20 + o];
    __syncthreads();
    int N2 = 2 * O;
    const float* P = Pg + (size_t)z * NPTS * N2;
    float tv = P[(size_t)n * N2 + O + o] - P[(size_t)n * N2 + o];
    float scl = ldw(g, o, isf) * BN_SCALE;
    float bv2 = ldw(bias, o, isf);
    float acc = -__builtin_inff();
    for (int j = 0; j < 20; j++) {
        int m = id[j];
        float v = P[(size_t)m * N2 + o] + tv;
        float z2 = v * scl + bv2;
        z2 = z2 > 0.f ? z2 : 0.2f * z2;
        acc = fmaxf(acc, z2);
    }
    bf16 hi = f2b(acc);
    bf16 lo = f2b(acc - b2f(hi));
    xhOut[(size_t)z * NPTS * 960 + (size_t)n * 960 + o] = hi;
    xlOut[(size_t)z * NPTS * 960 + (size_t)n * 960 + o] = lo;
    if (writeSq) {
        float xv = b2f(hi) + b2f(lo);
        float s = xv * xv;
#pragma unroll
        for (int off = 32; off > 0; off >>= 1) s += __shfl_down(s, off);
        if ((o & 63) == 0) red[o >> 6] = s;
        __syncthreads();
        if (o == 0) {
            float tot = 0.f;
            for (int i2 = 0; i2 < (O >> 6); i2++) tot += red[i2];
            sqOut[z * NPTS + n] = tot;
        }
    }
}

// ---------------- conv5 via MFMA (pre-split W5) + fused affine/lrelu/max-pool ----------------
__global__ __launch_bounds__(256) void k_conv5(const bf16* __restrict__ Xhi, const bf16* __restrict__ Xlo,
                                               const bf16* __restrict__ Whi, const bf16* __restrict__ Wlo,
                                               const void* __restrict__ g, const void* __restrict__ bias,
                                               unsigned* __restrict__ pooledU,
                                               const int* __restrict__ flag) {
    int isf = *flag;
    int z = blockIdx.z;
    const bf16* Xh = Xhi + (size_t)z * NPTS * 960;
    const bf16* Xl = Xlo + (size_t)z * NPTS * 960;
    __shared__ alignas(16) bf16 Ah[64 * TW], Al[64 * TW], Bh[64 * TW], Bl[64 * TW];
    __shared__ float red[4][4][16];
    int m0 = blockIdx.y * 64, o0 = blockIdx.x * 64;
    int w = threadIdx.x >> 6, l = threadIdx.x & 63;
    v4f zero = {0.f, 0.f, 0.f, 0.f};
    v4f acc[4] = {zero, zero, zero, zero};
    for (int k0 = 0; k0 < 960; k0 += 32) {
        __syncthreads();
        fillA(Ah, Xh + (size_t)m0 * 960 + k0, 960);
        fillA(Al, Xl + (size_t)m0 * 960 + k0, 960);
        fillA(Bh, Whi + (size_t)o0 * 960 + k0, 960);
        if (isf) fillA(Bl, Wlo + (size_t)o0 * 960 + k0, 960);
        __syncthreads();
        v8bf ah = ldfrag(Ah, w, l);
        v8bf al = ldfrag(Al, w, l);
#pragma unroll
        for (int nt = 0; nt < 4; nt++) {
            v8bf bh = ldfrag(Bh, nt, l);
            acc[nt] = __builtin_amdgcn_mfma_f32_16x16x32_bf16(ah, bh, acc[nt], 0, 0, 0);
            acc[nt] = __builtin_amdgcn_mfma_f32_16x16x32_bf16(al, bh, acc[nt], 0, 0, 0);
            if (isf) {
                v8bf bl = ldfrag(Bl, nt, l);
                acc[nt] = __builtin_amdgcn_mfma_f32_16x16x32_bf16(ah, bl, acc[nt], 0, 0, 0);
            }
        }
    }
    int quad = l >> 4, col = l & 15;
#pragma unroll
    for (int nt = 0; nt < 4; nt++) {
        int o = o0 + nt * 16 + col;
        float scl = ldw(g, o, isf) * BN_SCALE;
        float bi = ldw(bias, o, isf);
        float ym = -__builtin_inff();
#pragma unroll
        for (int r = 0; r < 4; r++) {
            float v = acc[nt][r] * scl + bi;
            v = v > 0.f ? v : 0.2f * v;
            ym = fmaxf(ym, v);
        }
        ym = fmaxf(ym, __shfl_down(ym, 32));
        ym = fmaxf(ym, __shfl_down(ym, 16));
        if (quad == 0) red[w][nt][col] = ym;
    }
    __syncthreads();
    if (threadIdx.x < 64) {
        int nt = threadIdx.x >> 4, c = threadIdx.x & 15;
        float m = fmaxf(fmaxf(red[0][nt][c], red[1][nt][c]), fmaxf(red[2][nt][c], red[3][nt][c]));
        atomicMax(&pooledU[z * 512 + o0 + nt * 16 + c], ordf(m));
    }
}

// ---------------- final linear: coalesced wave-per-output ----------------
__global__ void k_final(const unsigned* __restrict__ pooledU, const void* __restrict__ We,
                        void* __restrict__ out, const int* __restrict__ flag) {
    __shared__ float p[512];
    int isf = *flag;
    int b = blockIdx.x >> 2, fb = blockIdx.x & 3;
    int t = threadIdx.x, w = t >> 6, l = t & 63;
    for (int i = t; i < 512; i += 256) p[i] = iordf(pooledU[b * 512 + i]);
    __syncthreads();
    for (int it = 0; it < 16; it++) {
        int f = fb * 64 + w * 16 + it;
        float s = 0.f;
        size_t base = (size_t)f * 512 + l * 8;
#pragma unroll
        for (int j = 0; j < 8; j++) s += p[l * 8 + j] * ldw(We, base + j, isf);
#pragma unroll
        for (int off = 32; off > 0; off >>= 1) s += __shfl_down(s, off);
        if (l == 0) {
            if (isf) ((float*)out)[b * 256 + f] = s;
            else     ((bf16*)out)[b * 256 + f] = f2b(s);
        }
    }
}

extern "C" void kernel_launch(void* const* d_in, const int* in_sizes, int n_in,
                              void* d_out, int out_size, void* d_ws, size_t ws_size,
                              hipStream_t stream) {
    const void* x  = d_in[0];
    const void* Wl[4] = { d_in[1], d_in[4], d_in[7], d_in[10] };
    const void* gl[4] = { d_in[2], d_in[5], d_in[8], d_in[11] };
    const void* bl[4] = { d_in[3], d_in[6], d_in[9], d_in[12] };
    const void* W5 = d_in[13];
    const void* g5 = d_in[14];
    const void* b5 = d_in[15];
    const void* We = d_in[16];

    // workspace layout (bytes), total ~53.5 MB (ws ~256 MiB per round-9 fill evidence)
    char* base = (char*)d_ws;
    bf16*     xc_hi   = (bf16*)(base);                  // 7,864,320
    bf16*     xc_lo   = (bf16*)(base + 7864320);        // 7,864,320
    bf16*     xpadh   = (bf16*)(base + 15728640);       // 262,144
    bf16*     xpadl   = (bf16*)(base + 15990784);       // 262,144
    float*    Dbuf    = (float*)(base + 16252928);      // 16,777,216
    float*    Pbuf    = (float*)(base + 33030144);      // 16,777,216
    bf16*     Whi     = (bf16*)(base + 49807360);       // 1,679,360
    bf16*     Wlo     = (bf16*)(base + 51486720);       // 1,679,360
    int*      idxb    = (int*)(base + 53166080);        // 327,680
    unsigned* pooledU = (unsigned*)(base + 53493760);   // 8,192
    float*    sq      = (float*)(base + 53501952);      // 16,384
    int*      flag    = (int*)(base + 53518336);        // 4

    const int Kpad[4]   = { 32, 64, 128, 256 };
    const int Os[4]     = { 64, 128, 256, 512 };
    const int Woff[5]   = { 0, 4096, 20480, 86016, 348160 };
    const int colIn[4]  = { 0, 0, 64, 192 };
    const int colOut[4] = { 0, 64, 192, 448 };

    k_probe<<<1, 256, 0, stream>>>(x, flag, pooledU);
    k_prep<<<3296, 256, 0, stream>>>(Wl[0], Wl[1], Wl[2], Wl[3], W5, x,
                                     Whi, Wlo, xpadh, xpadl, sq, flag);

    for (int l = 0; l < 4; l++) {
        int O = Os[l];
        int nTilesO = (2 * O) >> 6;
        int nBlk = 136 + 16 * nTilesO;  // even for all layers
        const bf16* Xh = (l == 0) ? xpadh : (xc_hi + colIn[l]);
        const bf16* Xl = (l == 0) ? xpadl : (xc_lo + colIn[l]);
        int ld = (l == 0) ? 32 : 960;
        size_t xstr = (l == 0) ? (size_t)NPTS * 32 : (size_t)NPTS * 960;
        k_layer_a<<<nBlk * NB, 256, 0, stream>>>(
            Xh, Xl, ld, Kpad[l], xstr, Whi + Woff[l], Wlo + Woff[l], O, sq, Dbuf, Pbuf, flag);
        k_topk<<<dim3(NPTS / 4, NB), 256, 0, stream>>>(Dbuf, idxb);
        k_gmax<<<NPTS * NB, O, 0, stream>>>(
            Pbuf, idxb, gl[l], bl[l], O, xc_hi + colOut[l], xc_lo + colOut[l], sq, l < 3, flag);
    }
    k_conv5<<<dim3(8, 16, NB), 256, 0, stream>>>(xc_hi, xc_lo, Whi + Woff[4], Wlo + Woff[4],
                                                 g5, b5, pooledU, flag);
    k_final<<<16, 256, 0, stream>>>(pooledU, We, d_out, flag);
}